// Round 1
// baseline (129.132 us; speedup 1.0000x reference)
//
#include <hip/hip_runtime.h>

#define N_NODES 40000
#define C_DIM   128
#define K_NBR   16

// BETA = log(0.5/4 + 1) = log(1.125)
static constexpr float BETA_F = 0.11778303565638346f;
static constexpr float C1_F   = 0.7939952679092549f;   // (1-ALPHA)*(1-BETA)
static constexpr float C2_F   = 0.08822169643436166f;  // ALPHA*(1-BETA)

// ---------------------------------------------------------------------------
// Kernel 1a: build WcatT in float4-over-c layout.
// WcatTv[cb*128 + o] = (Wcat[4cb][o], Wcat[4cb+1][o], Wcat[4cb+2][o], Wcat[4cb+3][o])
// where Wcat[c][o] = (c < 128) ? W1[o][c] : W2[o][c-128].
// ---------------------------------------------------------------------------
__global__ void build_w_kernel(const float* __restrict__ W1,
                               const float* __restrict__ W2,
                               float4* __restrict__ WcatTv) {
    int i = blockIdx.x * blockDim.x + threadIdx.x;   // 0 .. 8191
    if (i >= 64 * 128) return;
    int cb = i >> 7;        // 0..63
    int o  = i & 127;       // 0..127
    float4 v;
    if (cb < 32) {
        const float* r = W1 + o * 128 + 4 * cb;
        v = make_float4(r[0], r[1], r[2], r[3]);
    } else {
        const float* r = W2 + o * 128 + (4 * cb - 128);
        v = make_float4(r[0], r[1], r[2], r[3]);
    }
    WcatTv[i] = v;
}

// ---------------------------------------------------------------------------
// Kernel 1b: transpose x [C=128][N=40000] -> xT [N][C]
// ---------------------------------------------------------------------------
__global__ void transpose_x_kernel(const float* __restrict__ x,
                                   float* __restrict__ xT) {
    __shared__ float tile[32][33];
    int nb = blockIdx.x * 32;
    int cb = blockIdx.y * 32;
    int tx = threadIdx.x;        // 0..31
    int ty = threadIdx.y;        // 0..7
#pragma unroll
    for (int i = 0; i < 32; i += 8)
        tile[ty + i][tx] = x[(size_t)(cb + ty + i) * N_NODES + nb + tx];
    __syncthreads();
#pragma unroll
    for (int i = 0; i < 32; i += 8)
        xT[(size_t)(nb + ty + i) * C_DIM + cb + tx] = tile[tx][ty + i];
}

// ---------------------------------------------------------------------------
// Kernel 2: fused gather-mean + dual GEMM + epilogue.
// Block = 256 threads (4 waves), 32 nodes per block, grid = 1250.
// ---------------------------------------------------------------------------
__global__ __launch_bounds__(256) void fused_kernel(
        const float*  __restrict__ xT,
        const float*  __restrict__ x0,
        const int*    __restrict__ e0,
        const float4* __restrict__ WcatTv,
        const float*  __restrict__ bias,
        float*        __restrict__ out) {
    __shared__ float y[32][256];   // [node][ aggr(128) | x0(128) ]  = 32 KB

    const int nb   = blockIdx.x * 32;
    const int wave = threadIdx.x >> 6;
    const int lane = threadIdx.x & 63;

    // ---- Phase 1: gather + mean, stage y tile ----
    const float inv_deg = 1.0f / 17.0f;
#pragma unroll 1
    for (int s = 0; s < 8; ++s) {
        const int local = wave * 8 + s;
        const int n     = nb + local;
        const float* xr = xT + (size_t)n * C_DIM;
        float a0 = xr[lane];
        float a1 = xr[64 + lane];
        const int* ei = e0 + (size_t)n * K_NBR;
#pragma unroll
        for (int k = 0; k < K_NBR; ++k) {
            const int j = ei[k];
            const float* xj = xT + (size_t)j * C_DIM;
            a0 += xj[lane];
            a1 += xj[64 + lane];
        }
        y[local][lane]      = a0 * inv_deg;
        y[local][64 + lane] = a1 * inv_deg;
        const float* x0r = x0 + (size_t)n * C_DIM;
        y[local][128 + lane] = x0r[lane];
        y[local][192 + lane] = x0r[64 + lane];
    }
    __syncthreads();

    // ---- Phase 2: GEMM  acc[nn] = sum_c y[n][c] * Wcat[c][o] ----
    const int o = threadIdx.x & 127;   // output channel
    const int g = threadIdx.x >> 7;    // node half: 0 or 1

    float acc[16];
#pragma unroll
    for (int nn = 0; nn < 16; ++nn) acc[nn] = 0.0f;

#pragma unroll 2
    for (int cb = 0; cb < 64; ++cb) {
        const float4 w = WcatTv[cb * 128 + o];
#pragma unroll
        for (int nn = 0; nn < 16; ++nn) {
            const float4 yv = *(const float4*)&y[g * 16 + nn][cb * 4];
            float a = acc[nn];
            a = fmaf(yv.x, w.x, a);
            a = fmaf(yv.y, w.y, a);
            a = fmaf(yv.z, w.z, a);
            a = fmaf(yv.w, w.w, a);
            acc[nn] = a;
        }
    }

    // ---- Phase 3: epilogue + store (out is [C][N]) ----
    const float bo = bias[o];
#pragma unroll
    for (int nn = 0; nn < 16; ++nn) {
        const int local = g * 16 + nn;
        const float aggr_v = y[local][o];
        const float x0_v   = y[local][128 + o];
        float v = fmaf(acc[nn], BETA_F,
                  fmaf(aggr_v, C1_F,
                  fmaf(x0_v,   C2_F, bo)));
        acc[nn] = v > 0.0f ? v : 0.0f;
    }
    float* op = out + (size_t)o * N_NODES + nb + g * 16;
#pragma unroll
    for (int nn = 0; nn < 16; nn += 4) {
        *(float4*)(op + nn) = make_float4(acc[nn], acc[nn + 1],
                                          acc[nn + 2], acc[nn + 3]);
    }
}

// ---------------------------------------------------------------------------
extern "C" void kernel_launch(void* const* d_in, const int* in_sizes, int n_in,
                              void* d_out, int out_size, void* d_ws, size_t ws_size,
                              hipStream_t stream) {
    const float* x    = (const float*)d_in[0];   // [1,128,40000,1]
    const float* x0   = (const float*)d_in[1];   // [1,40000,128]
    const int*   ei   = (const int*)  d_in[2];   // [2,1,40000,16]; use [0]
    const float* W1   = (const float*)d_in[3];   // [128,128]
    const float* W2   = (const float*)d_in[4];   // [128,128]
    const float* bias = (const float*)d_in[5];   // [1,1,128]
    float* out = (float*)d_out;                  // [1,128,40000,1]

    // ws layout: [0, 128KB) WcatTv ; [128KB, 128KB + 20.48MB) xT
    float4* WcatTv = (float4*)d_ws;
    float*  xT     = (float*)((char*)d_ws + 131072);

    hipLaunchKernelGGL(build_w_kernel, dim3(32), dim3(256), 0, stream,
                       W1, W2, WcatTv);
    hipLaunchKernelGGL(transpose_x_kernel, dim3(1250, 4), dim3(32, 8), 0, stream,
                       x, xT);
    hipLaunchKernelGGL(fused_kernel, dim3(1250), dim3(256), 0, stream,
                       xT, x0, ei, (const float4*)WcatTv, bias, out);
}

// Round 2
// 45.916 us; speedup vs baseline: 2.8123x; 2.8123x over previous
//
#include <hip/hip_runtime.h>

#define N_NODES 40000
#define C_DIM   128
#define K_NBR   16

static constexpr float BETA_F = 0.11778303565638346f;  // log(1.125)
static constexpr float C1_F   = 0.7939952679092549f;   // (1-ALPHA)*(1-BETA)
static constexpr float C2_F   = 0.08822169643436166f;  // ALPHA*(1-BETA)

typedef __attribute__((ext_vector_type(8))) short bf16x8;
typedef __attribute__((ext_vector_type(4))) float f32x4;

__device__ __forceinline__ unsigned pack_bf16x2(float a, float b) {
    unsigned ua = __float_as_uint(a), ub = __float_as_uint(b);
    ua += 0x7fffu + ((ua >> 16) & 1u);     // RNE
    ub += 0x7fffu + ((ub >> 16) & 1u);
    return (ua >> 16) | (ub & 0xffff0000u);
}
__device__ __forceinline__ float bflo(unsigned u) { return __uint_as_float(u << 16); }
__device__ __forceinline__ float bfhi(unsigned u) { return __uint_as_float(u & 0xffff0000u); }

// ---------------------------------------------------------------------------
// Kernel 1: build WBfrag — fragment-major bf16 W, matching the A-frag slot
// mapping: frag f = otile*8 + kblk; elem (lane, j) = Wcat[c][o] with
// c = kblk*32 + (lane>>4)*8 + j, o = otile*16 + (lane&15).
// Wcat[c][o] = c<128 ? W1[o][c] : W2[o][c-128].
// ---------------------------------------------------------------------------
__global__ void build_wfrag_kernel(const float* __restrict__ W1,
                                   const float* __restrict__ W2,
                                   unsigned short* __restrict__ WB) {
    int i = blockIdx.x * 256 + threadIdx.x;      // 0 .. 32767
    int frag   = i >> 9;                          // 0..63
    int within = i & 511;
    int lane = within >> 3, j = within & 7;
    int otile = frag >> 3, kblk = frag & 7;
    int o = otile * 16 + (lane & 15);
    int c = kblk * 32 + ((lane >> 4) << 3) + j;
    float w = (c < 128) ? W1[o * 128 + c] : W2[o * 128 + c - 128];
    unsigned u = __float_as_uint(w);
    u += 0x7fffu + ((u >> 16) & 1u);
    WB[i] = (unsigned short)(u >> 16);
}

// ---------------------------------------------------------------------------
// Kernel 2: transpose + cast  x [128][40000] f32  ->  xTb [40000][64] u32(bf16x2)
// ---------------------------------------------------------------------------
__global__ __launch_bounds__(256) void transpose_cast_kernel(
        const float* __restrict__ x, unsigned* __restrict__ xTb) {
    __shared__ float tile[32][33];
    const int nb = blockIdx.x * 32;
    const int cb = blockIdx.y * 32;
    const int tid = threadIdx.x;
    const int tx = tid & 31, ty = tid >> 5;
#pragma unroll
    for (int i = 0; i < 32; i += 8)
        tile[ty + i][tx] = x[(size_t)(cb + ty + i) * N_NODES + nb + tx];
    __syncthreads();
    const int nl = tid >> 3;        // 0..31
    const int cp = tid & 7;         // 0..7
#pragma unroll
    for (int it = 0; it < 2; ++it) {
        int cpl = cp + 8 * it;      // 0..15  (u32 col within the 32-c block)
        float a = tile[2 * cpl][nl];
        float b = tile[2 * cpl + 1][nl];
        xTb[(size_t)(nb + nl) * 64 + (cb >> 1) + cpl] = pack_bf16x2(a, b);
    }
}

// ---------------------------------------------------------------------------
// Kernel 3: fused gather-mean + MFMA dual-GEMM + epilogue.
// Block = 256 threads (4 waves), 32 nodes/block, grid = 1250.
// ---------------------------------------------------------------------------
__global__ __launch_bounds__(256) void fused2_kernel(
        const unsigned* __restrict__ xTb,     // [N][64] u32 = bf16x2
        const float*    __restrict__ x0,      // [N][128] f32
        const int*      __restrict__ e0,      // [N][16]
        const bf16x8*   __restrict__ WB,      // frag-major, 64 frags x 64 lanes
        const float*    __restrict__ bias,    // [128]
        float*          __restrict__ out) {   // [128][N]
    // y rows: 32 nodes; u32 cols: [0..63]=aggr bf16x2, [64..127]=x0 bf16x2, +4 pad
    __shared__ unsigned y[32][132];           // 16896 B ; row stride 528 B
    __shared__ int eis[512];

    const int nb   = blockIdx.x * 32;
    const int tid  = threadIdx.x;
    const int lane = tid & 63;
    const int wid  = tid >> 6;

    // stage edge indices (coalesced)
    eis[tid]       = e0[(size_t)nb * K_NBR + tid];
    eis[256 + tid] = e0[(size_t)nb * K_NBR + 256 + tid];
    __syncthreads();

    // ---- Phase 1: gather + mean -> y (bf16), stage x0 (bf16) ----
    const float inv_deg = 1.0f / 17.0f;
#pragma unroll 1
    for (int s = 0; s < 8; ++s) {
        const int local = wid * 8 + s;
        const int n = nb + local;
        unsigned u = xTb[(size_t)n * 64 + lane];
        float a0 = bflo(u), a1 = bfhi(u);
        const int* ep = &eis[local * K_NBR];
#pragma unroll
        for (int k = 0; k < K_NBR; ++k) {
            const int j = ep[k];
            unsigned v = xTb[(size_t)j * 64 + lane];
            a0 += bflo(v);
            a1 += bfhi(v);
        }
        y[local][lane] = pack_bf16x2(a0 * inv_deg, a1 * inv_deg);
        const float2 xv = *(const float2*)&x0[(size_t)n * C_DIM + 2 * lane];
        y[local][64 + lane] = pack_bf16x2(xv.x, xv.y);
    }
    __syncthreads();

    // ---- Phase 2: MFMA GEMM. wave -> (node half, o half) ----
    const int nh = wid & 1;        // 16-node half
    const int oh = wid >> 1;       // 64-o half
    const int arow = nh * 16 + (lane & 15);
    const int acol = (lane >> 4) * 4;           // u32 col base within k-block

    bf16x8 afrag[8];
#pragma unroll
    for (int kb = 0; kb < 8; ++kb)
        afrag[kb] = *(const bf16x8*)&y[arow][kb * 16 + acol];

    f32x4 acc[4];
#pragma unroll
    for (int t = 0; t < 4; ++t) {
        f32x4 a = {0.f, 0.f, 0.f, 0.f};
#pragma unroll
        for (int kb = 0; kb < 8; ++kb) {
            bf16x8 b = WB[((oh * 4 + t) * 8 + kb) * 64 + lane];
            a = __builtin_amdgcn_mfma_f32_16x16x32_bf16(afrag[kb], b, a, 0, 0, 0);
        }
        acc[t] = a;
    }

    // ---- Phase 3: epilogue + store. D: col=lane&15 (o), row=(lane>>4)*4+r (node)
    const int rbase = nh * 16 + (lane >> 4) * 4;
#pragma unroll
    for (int t = 0; t < 4; ++t) {
        const int o = oh * 64 + t * 16 + (lane & 15);
        const float bo = bias[o];
        const int oc = o >> 1;
        const bool hi = (o & 1) != 0;
        float res[4];
#pragma unroll
        for (int r = 0; r < 4; ++r) {
            const int row = rbase + r;
            const unsigned ua = y[row][oc];
            const unsigned ux = y[row][64 + oc];
            const float aggr = hi ? bfhi(ua) : bflo(ua);
            const float x0v  = hi ? bfhi(ux) : bflo(ux);
            float v = fmaf(acc[t][r], BETA_F,
                      fmaf(aggr, C1_F,
                      fmaf(x0v,  C2_F, bo)));
            res[r] = v > 0.0f ? v : 0.0f;
        }
        *(float4*)&out[(size_t)o * N_NODES + nb + rbase] =
            make_float4(res[0], res[1], res[2], res[3]);
    }
}

// ---------------------------------------------------------------------------
extern "C" void kernel_launch(void* const* d_in, const int* in_sizes, int n_in,
                              void* d_out, int out_size, void* d_ws, size_t ws_size,
                              hipStream_t stream) {
    const float* x    = (const float*)d_in[0];   // [1,128,40000,1]
    const float* x0   = (const float*)d_in[1];   // [1,40000,128]
    const int*   ei   = (const int*)  d_in[2];   // [2,1,40000,16]; row 0
    const float* W1   = (const float*)d_in[3];   // [128,128]
    const float* W2   = (const float*)d_in[4];   // [128,128]
    const float* bias = (const float*)d_in[5];   // [128]
    float* out = (float*)d_out;                  // [1,128,40000,1]

    // ws: [0, 64KB) WBfrag bf16 ; [64KB, 64KB+10.24MB) xTb
    unsigned short* WB  = (unsigned short*)d_ws;
    unsigned*       xTb = (unsigned*)((char*)d_ws + 65536);

    hipLaunchKernelGGL(build_wfrag_kernel, dim3(128), dim3(256), 0, stream,
                       W1, W2, WB);
    hipLaunchKernelGGL(transpose_cast_kernel, dim3(1250, 4), dim3(256), 0, stream,
                       x, xTb);
    hipLaunchKernelGGL(fused2_kernel, dim3(1250), dim3(256), 0, stream,
                       xTb, x0, ei, (const bf16x8*)WB, bias, out);
}